// Round 12
// baseline (133.893 us; speedup 1.0000x reference)
//
#include <hip/hip_runtime.h>

#define T_STEPS 345
#define B_SZ    128
#define IN_SZ   13
#define H_SZ    128
#define OUT_SZ  9
#define NBO     (B_SZ * OUT_SZ)   // 1152
#define CT      64                // t-chunk staged in LDS for the layer-1 scan
#define NC      6                 // ceil(345/64)
#define C2P     13                // c2 row pitch in floats (odd -> conflict-free)

typedef float v2f __attribute__((ext_vector_type(2)));

// One block = one batch element, fully fused, zero workspace use.
//  P0: cur1[t][h] precompute (parallel, pk_fma pairs — R5-proven bit-exact)
//  P1: mem1 scan = 3 VALU/step true critical path (chain verbatim R7 k1)
//  P2: cur2 bit-masked dot, W2^T in LDS, pk o-pairs (per-o chain == R8 k2)
//  P3: mem2 scan, parity-buffered burst stores (verbatim R11 k3 chain)
__global__ __launch_bounds__(384, 1)
void snn_fused2(const float* __restrict__ x, const float* __restrict__ W1,
                const float* __restrict__ b1, const float* __restrict__ W2,
                const float* __restrict__ b2, const float* __restrict__ beta1p,
                const float* __restrict__ thr1p, const float* __restrict__ beta2p,
                const float* __restrict__ thr2p, float* __restrict__ out)
{
    const int b   = blockIdx.x;
    const int tid = threadIdx.x;     // 0..383
    const int w   = tid >> 6;        // wave 0..5
    const int l   = tid & 63;

    __shared__ float cur1[CT * H_SZ];                         // 32,768 B
    __shared__ __align__(16) unsigned long long msk[352][2];  //  5,632 B
    __shared__ float w2t[H_SZ * 12];                          //  6,144 B
    __shared__ float c2[T_STEPS * C2P + 3];                   // 17,952 B
    // total 62,496 B < 64 KB/WG

    const float bt1 = fminf(fmaxf(beta1p[0], 0.0f), 1.0f);
    const float th1 = thr1p[0];
    const float bt2 = fminf(fmaxf(beta2p[0], 0.0f), 1.0f);
    const float th2 = thr2p[0];

    // stage W2^T: w2t[h*12 + o] = W2[o*128 + h], o>=9 zero-padded
    for (int i = tid; i < H_SZ * 12; i += 384) {
        const int h = i / 12, k = i - h * 12;
        w2t[i] = (k < OUT_SZ) ? W2[k * H_SZ + h] : 0.0f;
    }

    // per-thread layer-1 weights for pair (h=l, h=l+64) — every wave holds a copy
    v2f w1p[IN_SZ];
#pragma unroll
    for (int q = 0; q < IN_SZ; ++q)
        w1p[q] = (v2f){ W1[l * IN_SZ + q], W1[(l + 64) * IN_SZ + q] };
    const v2f b1p = (v2f){ b1[l], b1[l + 64] };

    const float* __restrict__ xb = x + (size_t)b * (IN_SZ * T_STEPS);

    float mem1 = 0.0f;   // P1 state, meaningful for tid<128 (h = tid)

    __syncthreads();

    // ================= chunked P0/P1 over T =================
    for (int c = 0; c < NC; ++c) {
        const int t0    = c * CT;
        const int steps = (T_STEPS - t0 < CT) ? (T_STEPS - t0) : CT;

        // ---- P0: cur1 for this chunk; wave w handles ti = w, w+6, ... ----
        {
            int ti = w;
            if (ti < steps) {
                float xv[IN_SZ], xn[IN_SZ];
#pragma unroll
                for (int q = 0; q < IN_SZ; ++q)
                    xv[q] = xb[q * T_STEPS + (t0 + ti)];          // wave-uniform
                for (; ti < steps; ti += 6) {
                    int tn = t0 + ti + 6;
                    tn = (tn < T_STEPS) ? tn : (T_STEPS - 1);      // clamp prefetch
#pragma unroll
                    for (int q = 0; q < IN_SZ; ++q)
                        xn[q] = xb[q * T_STEPS + tn];
                    // exact R5/R7 chain: cab = b1p; 13 fma in c-order (pk pair)
                    v2f cab = b1p;
#pragma unroll
                    for (int q = 0; q < IN_SZ; ++q) {
                        const v2f xq2 = (v2f){ xv[q], xv[q] };
                        cab = __builtin_elementwise_fma(xq2, w1p[q], cab);
                    }
                    cur1[ti * H_SZ + l]      = cab.x;
                    cur1[ti * H_SZ + 64 + l] = cab.y;
#pragma unroll
                    for (int q = 0; q < IN_SZ; ++q) xv[q] = xn[q];
                }
            }
        }
        __syncthreads();

        // ---- P1: mem1 scan of this chunk (tid < 128, h = tid) ----
        if (tid < 128) {
            float buf[2][8];
#pragma unroll
            for (int j = 0; j < 8; ++j) {
                const int s = (j < steps) ? j : (steps - 1);
                buf[0][j] = cur1[s * H_SZ + tid];
            }
#pragma unroll
            for (int blk = 0; blk < 8; ++blk) {
                if (blk * 8 >= steps) break;                       // uniform
                // preload next 8-step block
#pragma unroll
                for (int j = 0; j < 8; ++j) {
                    int s = (blk + 1) * 8 + j;
                    s = (s < steps) ? s : (steps - 1);
                    buf[(blk + 1) & 1][j] = cur1[s * H_SZ + tid];
                }
                // consume current block — chain verbatim R7 k1
#pragma unroll
                for (int j = 0; j < 8; ++j) {
                    const int s = blk * 8 + j;
                    if (s < steps) {
                        mem1 = fmaf(bt1, mem1, buf[blk & 1][j]);
                        const bool pa = mem1 > th1;
                        const unsigned long long m = __ballot(pa);
                        mem1 = fmaf(pa ? -1.0f : 0.0f, th1, mem1);
                        if ((tid & 63) == 0) msk[t0 + s][tid >> 6] = m;
                    }
                }
            }
        }
        __syncthreads();
    }

    // ================= P2: cur2[t][o], lane-per-t =================
    {
        const int  t      = (tid < T_STEPS) ? tid : (T_STEPS - 1);
        const bool active = tid < T_STEPS;
        const uint4 mm = *(const uint4*)&msk[t][0];

        v2f a01 = (v2f){0,0}, a23 = (v2f){0,0}, a45 = (v2f){0,0},
            a67 = (v2f){0,0}, a8x = (v2f){0,0};
        // h = 0..127 ascending; per-o component chain identical to R8 k2
#pragma unroll
        for (int d = 0; d < 4; ++d) {
            const unsigned mw = (d == 0) ? mm.x : (d == 1) ? mm.y
                              : (d == 2) ? mm.z : mm.w;
#pragma unroll
            for (int hh = 0; hh < 32; ++hh) {
                const int h = d * 32 + hh;
                const float bitf = (float)((mw >> hh) & 1u);
                const v2f bb = (v2f){ bitf, bitf };
                const v2f* wr = (const v2f*)&w2t[h * 12];   // broadcast LDS reads
                a01 = __builtin_elementwise_fma(bb, wr[0], a01);
                a23 = __builtin_elementwise_fma(bb, wr[1], a23);
                a45 = __builtin_elementwise_fma(bb, wr[2], a45);
                a67 = __builtin_elementwise_fma(bb, wr[3], a67);
                a8x = __builtin_elementwise_fma(bb, wr[4], a8x);
            }
        }
        if (active) {
            float* cr = &c2[t * C2P];
            cr[0] = a01.x + b2[0];  cr[1] = a01.y + b2[1];
            cr[2] = a23.x + b2[2];  cr[3] = a23.y + b2[3];
            cr[4] = a45.x + b2[4];  cr[5] = a45.y + b2[5];
            cr[6] = a67.x + b2[6];  cr[7] = a67.y + b2[7];
            cr[8] = a8x.x + b2[8];
        }
    }
    __syncthreads();

    // ================= P3: mem2 scan + burst stores (tid < 9) =================
    if (tid < OUT_SZ) {
        const int o = tid;
        float* __restrict__ out_spk = out + (size_t)b * OUT_SZ + o;
        float* __restrict__ out_mem = out + (size_t)T_STEPS * NBO + (size_t)b * OUT_SZ + o;

        float mem2 = 0.0f;
        float lb[2][16], sE[16], mE[16], sO[16], mO[16];
#pragma unroll
        for (int j = 0; j < 16; ++j) lb[0][j] = c2[j * C2P + o];

#pragma unroll
        for (int cc = 0; cc < 22; ++cc) {
            // preload next chunk (clamped)
#pragma unroll
            for (int j = 0; j < 16; ++j) {
                int tt = (cc + 1) * 16 + j;
                tt = (tt < T_STEPS) ? tt : (T_STEPS - 1);
                lb[(cc + 1) & 1][j] = c2[tt * C2P + o];
            }
            float* sB = (cc & 1) ? sO : sE;
            float* mB = (cc & 1) ? mO : mE;
            const int lim = (cc == 21) ? 9 : 16;   // 22*16=352, keep t<345
#pragma unroll
            for (int j = 0; j < 16; ++j) {
                if (j < lim) {
                    mem2 = fmaf(bt2, mem2, lb[cc & 1][j]);     // verbatim R11 chain
                    const float sp = (mem2 > th2) ? 1.0f : 0.0f;
                    mem2 = fmaf(-sp, th2, mem2);
                    sB[j] = sp; mB[j] = mem2;
                }
            }
            const size_t base = (size_t)cc * 16 * NBO;
#pragma unroll
            for (int j = 0; j < 16; ++j) {
                if (j < lim) {
                    out_spk[base + (size_t)j * NBO] = sB[j];
                    out_mem[base + (size_t)j * NBO] = mB[j];
                }
            }
        }
    }
}

extern "C" void kernel_launch(void* const* d_in, const int* in_sizes, int n_in,
                              void* d_out, int out_size, void* d_ws, size_t ws_size,
                              hipStream_t stream) {
    const float* x     = (const float*)d_in[0];
    const float* W1    = (const float*)d_in[1];
    const float* b1    = (const float*)d_in[2];
    const float* W2    = (const float*)d_in[3];
    const float* b2    = (const float*)d_in[4];
    const float* beta1 = (const float*)d_in[5];
    const float* thr1  = (const float*)d_in[6];
    const float* beta2 = (const float*)d_in[7];
    const float* thr2  = (const float*)d_in[8];
    float* out = (float*)d_out;

    snn_fused2<<<dim3(B_SZ), dim3(384), 0, stream>>>(
        x, W1, b1, W2, b2, beta1, thr1, beta2, thr2, out);
}